// Round 14
// baseline (140.915 us; speedup 1.0000x reference)
//
#include <hip/hip_runtime.h>
#include <stdint.h>

// ---------------------------------------------------------------------------
// CustomGPT2MultiHeadAttention: B=4, S=1024, SI=512, D=1024, H=16, Dh=64
// Round 14: KV-split attention — 2048 blocks (2 halves x 12 KV-tiles), each
// writes UNNORMALIZED partials (bf16 O, f32 l; max-free softmax => merge is
// pure addition); streaming merge kernel normalizes into Qb (dead post-attn).
// gemm_qkv reverted to round-11 exact. gemm_out unchanged.
// ---------------------------------------------------------------------------

typedef unsigned short u16;
typedef short bf16x8v __attribute__((ext_vector_type(8)));
typedef float f32x4 __attribute__((ext_vector_type(4)));

__device__ __forceinline__ u16 f2bf(float f) {
  union { float f; uint32_t u; } x; x.f = f;
  uint32_t r = x.u + 0x7FFFu + ((x.u >> 16) & 1u);   // round-to-nearest-even
  return (u16)(r >> 16);
}

// v_cvt_pk_bf16_f32: D[15:0]=bf16(a), D[31:16]=bf16(b), RNE
__device__ __forceinline__ uint32_t cvtpk(float a, float b) {
  uint32_t r;
  asm("v_cvt_pk_bf16_f32 %0, %1, %2" : "=v"(r) : "v"(a), "v"(b));
  return r;
}

// p = bit(msrc,off) ? e : 0   via sign-extended 1-bit field + AND (2 VALU)
__device__ __forceinline__ float maskand(float e, uint32_t msrc, int off) {
  uint32_t mm = (uint32_t)((int32_t)(msrc << (31 - off)) >> 31);
  union { float f; uint32_t u; } x; x.f = e; x.u &= mm; return x.f;
}

__device__ __forceinline__ void gl_lds16(const u16* g, u16* l) {
  __builtin_amdgcn_global_load_lds((const __attribute__((address_space(1))) unsigned int*)g,
                                   (__attribute__((address_space(3))) unsigned int*)l,
                                   16, 0, 0);
}

// ---------------------------------------------------------------------------
// Fused QKV GEMM (round-11 exact): 256x256 tile, BK=64, 512 thr / 8 waves,
// dbuf, fp32 inputs with in-kernel cast, fused mask bit-pack, vectorized
// V-epilogue, XCD-affine remap.
__global__ __launch_bounds__(512, 2) void gemm_qkv(
    const float* __restrict__ Hs, const float* __restrict__ Im,
    const float* __restrict__ Wq, const float* __restrict__ Wk, const float* __restrict__ Wv,
    const float* __restrict__ Uk, const float* __restrict__ Uv,
    const int* __restrict__ Mk,
    u16* __restrict__ Qd, u16* __restrict__ Kd, u16* __restrict__ Vd,
    uint32_t* __restrict__ Mw)
{
  __shared__ __align__(16) u16 As[2 * 16384];   // 64 KB
  __shared__ __align__(16) u16 Bs[2 * 16384];   // 64 KB
  const int hb = blockIdx.x;
  const int xcd = hb & 7, slot = hb >> 3;
  int bid = (slot < 24) ? xcd * 24 + slot : 192 + xcd * 8 + (slot - 24);
  const float *Ap, *Bp;
  int bm, bn, mode;
  if (bid < 192) { mode = 4; bm = (bid / 12) * 256; bn = (bid % 12) * 256;
                   Ap = Hs + (size_t)bm * 1024;
                   Bp = ((bn < 1024) ? Wq : (bn < 2048) ? Wk : Wv) + (size_t)(bn & 1023) * 1024; }
  else           { mode = 5; int r = bid - 192; bm = (r >> 3) * 256; bn = (r & 7) * 256;
                   Ap = Im + (size_t)bm * 1024;
                   Bp = ((bn < 1024) ? Uk : Uv) + (size_t)(bn & 1023) * 1024; }
  const int tid = threadIdx.x, lane = tid & 63, wave = tid >> 6;
  const int wr = wave >> 2, wc = wave & 3;      // 2M x 4N
  const int g = lane >> 4, c = lane & 15, cs = c & 7;
  const int srow = tid >> 3;                    // 0..63
  const int pch  = tid & 7;
  const int gsw  = (pch ^ (srow & 7)) * 8;      // pre-swizzled global elem chunk

  f32x4 zf = {0.f, 0.f, 0.f, 0.f};
  f32x4 acc[8][4];
  #pragma unroll
  for (int f = 0; f < 8; ++f)
    #pragma unroll
    for (int nf = 0; nf < 4; ++nf) acc[f][nf] = zf;

  float4 sa[4][2], sb[4][2];

  #define LOAD_A(kt)                                                               \
    _Pragma("unroll")                                                              \
    for (int j_ = 0; j_ < 4; ++j_) {                                               \
      const float* p_ = Ap + (size_t)(j_ * 64 + srow) * 1024 + (kt) * 64 + gsw;    \
      sa[j_][0] = *(const float4*)p_;                                              \
      sa[j_][1] = *(const float4*)(p_ + 4);                                        \
    }
  #define LOAD_B(kt)                                                               \
    _Pragma("unroll")                                                              \
    for (int j_ = 0; j_ < 4; ++j_) {                                               \
      const float* p_ = Bp + (size_t)(j_ * 64 + srow) * 1024 + (kt) * 64 + gsw;    \
      sb[j_][0] = *(const float4*)p_;                                              \
      sb[j_][1] = *(const float4*)(p_ + 4);                                        \
    }
  #define CVT_A(buf)                                                               \
    _Pragma("unroll")                                                              \
    for (int j_ = 0; j_ < 4; ++j_) {                                               \
      uint4 w_;                                                                    \
      w_.x = cvtpk(sa[j_][0].x, sa[j_][0].y);                                      \
      w_.y = cvtpk(sa[j_][0].z, sa[j_][0].w);                                      \
      w_.z = cvtpk(sa[j_][1].x, sa[j_][1].y);                                      \
      w_.w = cvtpk(sa[j_][1].z, sa[j_][1].w);                                      \
      *(uint4*)&As[(buf) + (j_ * 64 + srow) * 64 + pch * 8] = w_;                  \
    }
  #define CVT_B(buf)                                                               \
    _Pragma("unroll")                                                              \
    for (int j_ = 0; j_ < 4; ++j_) {                                               \
      uint4 w_;                                                                    \
      w_.x = cvtpk(sb[j_][0].x, sb[j_][0].y);                                      \
      w_.y = cvtpk(sb[j_][0].z, sb[j_][0].w);                                      \
      w_.z = cvtpk(sb[j_][1].x, sb[j_][1].y);                                      \
      w_.w = cvtpk(sb[j_][1].z, sb[j_][1].w);                                      \
      *(uint4*)&Bs[(buf) + (j_ * 64 + srow) * 64 + pch * 8] = w_;                  \
    }

  // prologue: issue tile-0 loads, then pack mask (overlaps tile-0 latency)
  LOAD_A(0); LOAD_B(0);
  {
    const int fid = hb * 512 + tid;   // 131,072 threads; 196,608 words
    #pragma unroll 1
    for (int w = fid; w < 196608; w += 131072) {
      const int4* p = (const int4*)(Mk + (size_t)w * 32);
      uint32_t bits = 0;
      #pragma unroll 1
      for (int h_ = 0; h_ < 2; ++h_) {       // two batches of 4 int4 (reg cap)
        int4 v0 = p[h_ * 4 + 0], v1 = p[h_ * 4 + 1];
        int4 v2 = p[h_ * 4 + 2], v3 = p[h_ * 4 + 3];
        int bo = h_ * 16;
        bits |= (uint32_t)(v0.x != 0) << (bo + 0);
        bits |= (uint32_t)(v0.y != 0) << (bo + 1);
        bits |= (uint32_t)(v0.z != 0) << (bo + 2);
        bits |= (uint32_t)(v0.w != 0) << (bo + 3);
        bits |= (uint32_t)(v1.x != 0) << (bo + 4);
        bits |= (uint32_t)(v1.y != 0) << (bo + 5);
        bits |= (uint32_t)(v1.z != 0) << (bo + 6);
        bits |= (uint32_t)(v1.w != 0) << (bo + 7);
        bits |= (uint32_t)(v2.x != 0) << (bo + 8);
        bits |= (uint32_t)(v2.y != 0) << (bo + 9);
        bits |= (uint32_t)(v2.z != 0) << (bo + 10);
        bits |= (uint32_t)(v2.w != 0) << (bo + 11);
        bits |= (uint32_t)(v3.x != 0) << (bo + 12);
        bits |= (uint32_t)(v3.y != 0) << (bo + 13);
        bits |= (uint32_t)(v3.z != 0) << (bo + 14);
        bits |= (uint32_t)(v3.w != 0) << (bo + 15);
      }
      Mw[w] = bits;
    }
  }
  CVT_A(0);  CVT_B(0);
  __syncthreads();

  for (int kt = 0; kt < 16; ++kt) {
    const int bc = (kt & 1) * 16384;
    const int bx = bc ^ 16384;
    if (kt < 15) LOAD_A(kt + 1);       // fire-and-forget, lands during phases 0-1

    bf16x8v Bf[4][2];
    #pragma unroll
    for (int nf = 0; nf < 4; ++nf)
      #pragma unroll
      for (int ks = 0; ks < 2; ++ks)
        Bf[nf][ks] = *(const bf16x8v*)&Bs[bc + (wc * 64 + nf * 16 + c) * 64 + ((ks * 4 + g) ^ cs) * 8];

    #pragma unroll
    for (int p = 0; p < 4; ++p) {
      bf16x8v Af[2][2];
      #pragma unroll
      for (int i = 0; i < 2; ++i)
        #pragma unroll
        for (int ks = 0; ks < 2; ++ks)
          Af[i][ks] = *(const bf16x8v*)&As[bc + (wr * 128 + (p * 2 + i) * 16 + c) * 64 + ((ks * 4 + g) ^ cs) * 8];
      __builtin_amdgcn_s_setprio(1);
      #pragma unroll
      for (int i = 0; i < 2; ++i)
        #pragma unroll
        for (int nf = 0; nf < 4; ++nf)
          #pragma unroll
          for (int ks = 0; ks < 2; ++ks)
            acc[p * 2 + i][nf] =
              __builtin_amdgcn_mfma_f32_16x16x32_bf16(Af[i][ks], Bf[nf][ks], acc[p * 2 + i][nf], 0, 0, 0);
      __builtin_amdgcn_s_setprio(0);
      if (p == 1 && kt < 15) {
        __builtin_amdgcn_sched_barrier(0);   // keep cvt below phases 0-1
        CVT_A(bx);                           // A regs landed; write buf bx
        LOAD_B(kt + 1);                      // B loads land during phases 2-3
        __builtin_amdgcn_sched_barrier(0);
      }
    }
    if (kt < 15) {
      __builtin_amdgcn_sched_barrier(0);
      CVT_B(bx);
    }
    __syncthreads();                         // reads of bc done; bx writes visible
  }
  #undef LOAD_A
  #undef LOAD_B
  #undef CVT_A
  #undef CVT_B

  // epilogue — whole block is ONE region (bn is 256-aligned)
  const int gn0 = bn + wc * 64;
  if (mode == 4) {
    if (bn < 1024) {
      #pragma unroll
      for (int f = 0; f < 8; ++f)
        #pragma unroll
        for (int nf = 0; nf < 4; ++nf) {
          int gm = bm + wr * 128 + f * 16 + 4 * g;
          int gn = gn0 + nf * 16 + c;
          #pragma unroll
          for (int j = 0; j < 4; ++j)
            Qd[(size_t)(gm + j) * 1024 + gn] = f2bf(acc[f][nf][j] * 0.18033688011112042f);
        }
    } else if (bn < 2048) {
      #pragma unroll
      for (int f = 0; f < 8; ++f)
        #pragma unroll
        for (int nf = 0; nf < 4; ++nf) {
          int gm = bm + wr * 128 + f * 16 + 4 * g;
          int b_ = gm >> 10, s_ = gm & 1023;
          int gn = gn0 - 1024 + nf * 16 + c;
          #pragma unroll
          for (int j = 0; j < 4; ++j)
            Kd[(size_t)(b_ * 1536 + s_ + j) * 1024 + gn] = f2bf(acc[f][nf][j]);
        }
    } else {
      #pragma unroll
      for (int f = 0; f < 8; ++f)
        #pragma unroll
        for (int nf = 0; nf < 4; ++nf) {
          int gm = bm + wr * 128 + f * 16 + 4 * g;
          int b_ = gm >> 10, s_ = gm & 1023;
          int d_ = gn0 - 2048 + nf * 16 + c;
          uint2 st;
          st.x = cvtpk(acc[f][nf][0], acc[f][nf][1]);
          st.y = cvtpk(acc[f][nf][2], acc[f][nf][3]);
          *(uint2*)&Vd[(size_t)(b_ * 1024 + d_) * 1536 + s_] = st;
        }
    }
  } else {
    if (bn < 1024) {
      #pragma unroll
      for (int f = 0; f < 8; ++f)
        #pragma unroll
        for (int nf = 0; nf < 4; ++nf) {
          int gm = bm + wr * 128 + f * 16 + 4 * g;
          int b_ = gm >> 9, s_ = gm & 511;
          int gn = gn0 + nf * 16 + c;
          #pragma unroll
          for (int j = 0; j < 4; ++j)
            Kd[(size_t)(b_ * 1536 + 1024 + s_ + j) * 1024 + gn] = f2bf(acc[f][nf][j]);
        }
    } else {
      #pragma unroll
      for (int f = 0; f < 8; ++f)
        #pragma unroll
        for (int nf = 0; nf < 4; ++nf) {
          int gm = bm + wr * 128 + f * 16 + 4 * g;
          int b_ = gm >> 9, s_ = gm & 511;
          int d_ = gn0 - 1024 + nf * 16 + c;
          uint2 st;
          st.x = cvtpk(acc[f][nf][0], acc[f][nf][1]);
          st.y = cvtpk(acc[f][nf][2], acc[f][nf][3]);
          *(uint2*)&Vd[(size_t)(b_ * 1024 + d_) * 1536 + 1024 + s_] = st;
        }
    }
  }
}

// ---------------------------------------------------------------------------
// out-proj GEMM: 128x128 tile, BK=64, 256 thr / 4 waves, dbuf.
// A = merged attn-out bf16 via gl_lds; B = w_o fp32 reg-staged.
__global__ __launch_bounds__(256) void gemm_out(const u16* __restrict__ A, const float* __restrict__ Bw,
                                                float* __restrict__ Cout)
{
  __shared__ __align__(16) u16 As2[2 * 8192];   // 32 KB
  __shared__ __align__(16) u16 Bs2[2 * 8192];   // 32 KB
  const int hb = blockIdx.x;
  const int xcd = hb & 7, slot = hb >> 3;       // slot 0..31
  const int rg = xcd * 4 + (slot >> 3);         // 0..31
  const int cg = slot & 7;                      // 0..7
  const int bm = rg * 128, bn = cg * 128;
  const int tid  = threadIdx.x;
  const int lane = tid & 63, wave = tid >> 6;
  const int wr = wave >> 1, wc = wave & 1;
  const int g = lane >> 4, c = lane & 15, cs = c & 7;
  const int sr  = tid >> 3;                     // 0..31
  const int pch = tid & 7;
  const int gsw = (pch ^ (sr & 7)) * 8;

  f32x4 zf = {0.f, 0.f, 0.f, 0.f};
  f32x4 acc[4][4];
  #pragma unroll
  for (int mi = 0; mi < 4; ++mi)
    #pragma unroll
    for (int ni = 0; ni < 4; ++ni) acc[mi][ni] = zf;

  float4 sb[4][2];

  #define STG_A(buf, kt)                                                           \
    _Pragma("unroll")                                                              \
    for (int q_ = 0; q_ < 4; ++q_) {                                               \
      int row_ = q_ * 32 + sr;                                                     \
      gl_lds16(A + (size_t)(bm + row_) * 1024 + (kt) * 64 + gsw,                   \
               &As2[(buf) + row_ * 64 + pch * 8]);                                 \
    }
  #define LOAD_B(kt)                                                               \
    _Pragma("unroll")                                                              \
    for (int q_ = 0; q_ < 4; ++q_) {                                               \
      const float* p_ = Bw + (size_t)(bn + q_ * 32 + sr) * 1024 + (kt) * 64 + gsw; \
      sb[q_][0] = *(const float4*)p_;                                              \
      sb[q_][1] = *(const float4*)(p_ + 4);                                        \
    }
  #define CVT_B(buf)                                                               \
    _Pragma("unroll")                                                              \
    for (int q_ = 0; q_ < 4; ++q_) {                                               \
      uint4 w_;                                                                    \
      w_.x = cvtpk(sb[q_][0].x, sb[q_][0].y);                                      \
      w_.y = cvtpk(sb[q_][0].z, sb[q_][0].w);                                      \
      w_.z = cvtpk(sb[q_][1].x, sb[q_][1].y);                                      \
      w_.w = cvtpk(sb[q_][1].z, sb[q_][1].w);                                      \
      *(uint4*)&Bs2[(buf) + (q_ * 32 + sr) * 64 + pch * 8] = w_;                   \
    }

  STG_A(0, 0);
  LOAD_B(0);
  CVT_B(0);
  __syncthreads();

  for (int kt = 0; kt < 16; ++kt) {
    const int bc = (kt & 1) * 8192;
    const int bx = bc ^ 8192;
    if (kt < 15) { STG_A(bx, kt + 1); LOAD_B(kt + 1); }

    #pragma unroll
    for (int ks = 0; ks < 2; ++ks) {
      bf16x8v af[4], bfr[4];
      #pragma unroll
      for (int mi = 0; mi < 4; ++mi)
        af[mi] = *(const bf16x8v*)&As2[bc + (wr * 64 + mi * 16 + c) * 64 + ((ks * 4 + g) ^ cs) * 8];
      #pragma unroll
      for (int ni = 0; ni < 4; ++ni)
        bfr[ni] = *(const bf16x8v*)&Bs2[bc + (wc * 64 + ni * 16 + c) * 64 + ((ks * 4 + g) ^ cs) * 8];
      __builtin_amdgcn_s_setprio(1);
      #pragma unroll
      for (int mi = 0; mi < 4; ++mi)
        #pragma unroll
        for (int ni = 0; ni < 4; ++ni)
          acc[mi][ni] = __builtin_amdgcn_mfma_f32_16x16x32_bf16(af[mi], bfr[ni], acc[mi][ni], 0, 0, 0);
      __builtin_amdgcn_s_setprio(0);
    }
    if (kt < 15) {
      __builtin_amdgcn_sched_barrier(0);
      CVT_B(bx);
    }
    __syncthreads();
  }
  #undef STG_A
  #undef LOAD_B
  #undef CVT_B

  #pragma unroll
  for (int mi = 0; mi < 4; ++mi)
    #pragma unroll
    for (int ni = 0; ni < 4; ++ni)
      #pragma unroll
      for (int j = 0; j < 4; ++j) {
        int gm = bm + wr * 64 + mi * 16 + 4 * g + j;
        int gn = bn + wc * 64 + ni * 16 + c;
        Cout[(size_t)gm * 1024 + gn] = acc[mi][ni][j];
      }
}

// ---------------------------------------------------------------------------
// flash attention, swapped QK^T, max-free softmax, KV-SPLIT (2 halves).
// Grid 2048: grp = bid&63 (b,h; XCD = bid%8), qt = (bid>>6)&15, half = bid>>10.
// Each block: 12 KV-tiles; writes UNNORMALIZED O (bf16) + denominator l (f32).
__global__ __launch_bounds__(256) void attn_kernel(const u16* __restrict__ Q, const u16* __restrict__ Kc,
                                                   const u16* __restrict__ Vt,
                                                   const uint32_t* __restrict__ Mw,
                                                   u16* __restrict__ Op0, u16* __restrict__ Op1,
                                                   float* __restrict__ Lp0, float* __restrict__ Lp1)
{
  const int bid = blockIdx.x;
  const int grp = bid & 63;
  const int qt  = (bid >> 6) & 15;
  const int half = bid >> 10;
  const int h = grp & 15, b = grp >> 4;
  const int q0 = qt * 64;
  const int tid = threadIdx.x, lane = tid & 63, wave = tid >> 6;
  const int g = lane >> 4, c = lane & 15;
  const int qw = q0 + wave * 16;
  u16*  Op = half ? Op1 : Op0;
  float* Lp = half ? Lp1 : Lp0;
  const int kt0 = half * 12;

  __shared__ __align__(16) u16 Ks[64 * 64];      // 8 KB
  __shared__ __align__(16) u16 Vs[64 * 64];      // 8 KB  [d][l]
  __shared__ __align__(16) u16 Ps[4][16 * 72];   // 9 KB  per-wave P, padded

  bf16x8v qf0, qf1;
  {
    const u16* qp = Q + (size_t)(b * 1024 + qw + c) * 1024 + h * 64 + g * 8;
    qf0 = *(const bf16x8v*)qp;
    qf1 = *(const bf16x8v*)(qp + 32);
  }
  f32x4 zf = {0.f, 0.f, 0.f, 0.f};
  f32x4 O[4];                       // O^T frag: [d=dt*16+4g+j][q=c]
  float l = 0.f;                    // per-lane partial denominator
  #pragma unroll
  for (int dt = 0; dt < 4; ++dt) O[dt] = zf;

  const int sr  = tid >> 3;         // 0..31
  const int pch = tid & 7;
  const int swz = (pch ^ (sr & 7)) * 8;   // write-side XOR swizzle
  const int cs  = c & 7;
  const u16* Kbase = Kc + (size_t)(b * 1536) * 1024 + h * 64;
  const u16* Vbase = Vt + (size_t)(b * 1024 + h * 64) * 1536;
  const uint32_t* mrow = Mw + (size_t)(b * 1024 + qw + c) * 48;

  bf16x8v kr0, kr1, vr0, vr1;
  {
    const int l0 = kt0 * 64;
    kr0 = *(const bf16x8v*)(Kbase + (size_t)(l0 + sr) * 1024 + pch * 8);
    kr1 = *(const bf16x8v*)(Kbase + (size_t)(l0 + 32 + sr) * 1024 + pch * 8);
    vr0 = *(const bf16x8v*)(Vbase + (size_t)sr * 1536 + l0 + pch * 8);
    vr1 = *(const bf16x8v*)(Vbase + (size_t)(32 + sr) * 1536 + l0 + pch * 8);
  }
  *(bf16x8v*)&Ks[sr * 64 + swz]        = kr0;
  *(bf16x8v*)&Ks[(32 + sr) * 64 + swz] = kr1;
  *(bf16x8v*)&Vs[sr * 64 + swz]        = vr0;
  *(bf16x8v*)&Vs[(32 + sr) * 64 + swz] = vr1;
  __syncthreads();

  for (int kt = kt0; kt < kt0 + 12; ++kt) {
    if (kt < kt0 + 11) {
      const int ln = (kt + 1) * 64;
      kr0 = *(const bf16x8v*)(Kbase + (size_t)(ln + sr) * 1024 + pch * 8);
      kr1 = *(const bf16x8v*)(Kbase + (size_t)(ln + 32 + sr) * 1024 + pch * 8);
      vr0 = *(const bf16x8v*)(Vbase + (size_t)sr * 1536 + ln + pch * 8);
      vr1 = *(const bf16x8v*)(Vbase + (size_t)(32 + sr) * 1536 + ln + pch * 8);
    }
    uint2 mwv = *(const uint2*)(mrow + kt * 2);

    f32x4 s[4];
    __builtin_amdgcn_s_setprio(1);
    #pragma unroll
    for (int nt = 0; nt < 4; ++nt) {
      const u16* kr = &Ks[(nt * 16 + c) * 64];
      bf16x8v k0 = *(const bf16x8v*)&kr[(g ^ cs) * 8];
      bf16x8v k1 = *(const bf16x8v*)&kr[((4 + g) ^ cs) * 8];
      f32x4 z = zf;
      z = __builtin_amdgcn_mfma_f32_16x16x32_bf16(k0, qf0, z, 0, 0, 0);
      z = __builtin_amdgcn_mfma_f32_16x16x32_bf16(k1, qf1, z, 0, 0, 0);
      s[nt] = z;
    }
    __builtin_amdgcn_s_setprio(0);

    uint64_t mq = (((uint64_t)mwv.y << 32) | (uint64_t)mwv.x) >> (4 * g);
    uint32_t mlo = (uint32_t)mq, mhi = (uint32_t)(mq >> 32);
    #pragma unroll
    for (int nt = 0; nt < 4; ++nt) {
      uint32_t msrc = (nt < 2) ? mlo : mhi;
      #pragma unroll
      for (int j = 0; j < 4; ++j) {
        float e = exp2f(s[nt][j]);
        float p = maskand(e, msrc, 16 * (nt & 1) + j);
        s[nt][j] = p;
        l += p;
      }
    }

    u16* pw = &Ps[wave][0];
    #pragma unroll
    for (int nt = 0; nt < 4; ++nt) {
      uint2 pk2;
      pk2.x = cvtpk(s[nt][0], s[nt][1]);
      pk2.y = cvtpk(s[nt][2], s[nt][3]);
      *(uint2*)&pw[c * 72 + nt * 16 + g * 4] = pk2;
    }
    bf16x8v pb0 = *(const bf16x8v*)&pw[c * 72 + g * 8];
    bf16x8v pb1 = *(const bf16x8v*)&pw[c * 72 + 32 + g * 8];
    __builtin_amdgcn_s_setprio(1);
    #pragma unroll
    for (int dt = 0; dt < 4; ++dt) {
      const u16* vr = &Vs[(dt * 16 + c) * 64];
      bf16x8v v0 = *(const bf16x8v*)&vr[(g ^ cs) * 8];
      bf16x8v v1 = *(const bf16x8v*)&vr[((4 + g) ^ cs) * 8];
      O[dt] = __builtin_amdgcn_mfma_f32_16x16x32_bf16(v0, pb0, O[dt], 0, 0, 0);
      O[dt] = __builtin_amdgcn_mfma_f32_16x16x32_bf16(v1, pb1, O[dt], 0, 0, 0);
    }
    __builtin_amdgcn_s_setprio(0);

    __syncthreads();                 // all waves done READING Ks/Vs
    if (kt < kt0 + 11) {
      *(bf16x8v*)&Ks[sr * 64 + swz]        = kr0;
      *(bf16x8v*)&Ks[(32 + sr) * 64 + swz] = kr1;
      *(bf16x8v*)&Vs[sr * 64 + swz]        = vr0;
      *(bf16x8v*)&Vs[(32 + sr) * 64 + swz] = vr1;
      __syncthreads();
    }
  }

  // partial epilogue: denominator (full cross-g reduce) + UNNORMALIZED O
  float r = l;
  r += __shfl_xor(r, 16);
  r += __shfl_xor(r, 32);
  const int row = b * 1024 + qw + c;
  if (lane < 16) Lp[(size_t)row * 16 + h] = r;
  size_t ro = (size_t)row * 1024 + h * 64;
  #pragma unroll
  for (int dt = 0; dt < 4; ++dt) {
    uint2 st;
    st.x = cvtpk(O[dt][0], O[dt][1]);
    st.y = cvtpk(O[dt][2], O[dt][3]);
    *(uint2*)&Op[ro + dt * 16 + 4 * g] = st;
  }
}

// ---------------------------------------------------------------------------
// merge: AO = (O0 + O1) / (l0 + l1), bf16 out. 8,388,608 elems / 8 per thread.
__global__ __launch_bounds__(256) void attn_merge(const u16* __restrict__ Op0, const u16* __restrict__ Op1,
                                                  const float* __restrict__ Lp0, const float* __restrict__ Lp1,
                                                  u16* __restrict__ AO)
{
  const int i = blockIdx.x * 256 + threadIdx.x;   // 0..1,048,575
  const size_t flat = (size_t)i * 8;
  const int row = i >> 7;
  const int h = (i >> 3) & 15;
  const float inv = 1.f / (Lp0[(size_t)row * 16 + h] + Lp1[(size_t)row * 16 + h]);
  uint4 a = *(const uint4*)(Op0 + flat);
  uint4 b = *(const uint4*)(Op1 + flat);
  uint4 o;
  #pragma unroll
  for (int w = 0; w < 4; ++w) {
    uint32_t au = (&a.x)[w], bu = (&b.x)[w];
    union { uint32_t u; float f; } al, ah, bl, bh;
    al.u = au << 16; ah.u = au & 0xFFFF0000u;
    bl.u = bu << 16; bh.u = bu & 0xFFFF0000u;
    (&o.x)[w] = cvtpk((al.f + bl.f) * inv, (ah.f + bh.f) * inv);
  }
  *(uint4*)(AO + flat) = o;
}

// ---------------------------------------------------------------------------
extern "C" void kernel_launch(void* const* d_in, const int* in_sizes, int n_in,
                              void* d_out, int out_size, void* d_ws, size_t ws_size,
                              hipStream_t stream) {
  (void)in_sizes; (void)n_in; (void)out_size; (void)ws_size;
  const float* hs = (const float*)d_in[0];
  const float* im = (const float*)d_in[1];
  const int*   mk = (const int*)d_in[2];
  const float* wq = (const float*)d_in[3];
  const float* wk = (const float*)d_in[4];
  const float* wv = (const float*)d_in[5];
  const float* uk = (const float*)d_in[6];
  const float* uv = (const float*)d_in[7];
  const float* wo = (const float*)d_in[8];

  char* ws = (char*)d_ws;
  u16* Qb  = (u16*)(ws + 0);          //  8,388,608 B  Q (pre-scaled); REUSED as AO by merge
  u16* Kb  = (u16*)(ws + 8388608);    // 12,582,912 B  K concat [4][1536][1024]
  u16* Vtb = (u16*)(ws + 20971520);   // 12,582,912 B  V transposed [4][1024][1536]
  uint32_t* Mw = (uint32_t*)(ws + 33554432); // 786,432 B packed mask
  u16* Op0 = (u16*)(ws + 34340864);   //  8,388,608 B  partial O half 0 (bf16)
  u16* Op1 = (u16*)(ws + 42729472);   //  8,388,608 B  partial O half 1 (bf16)
  float* Lp0 = (float*)(ws + 51118080);  // 262,144 B  partial l half 0
  float* Lp1 = (float*)(ws + 51380224); // 262,144 B  partial l half 1
  // total ws: 51,642,368 B (< 59.5 MB proven available)

  gemm_qkv<<<256, 512, 0, stream>>>(hs, im, wq, wk, wv, uk, uv, mk, Qb, Kb, Vtb, Mw);
  attn_kernel<<<2048, 256, 0, stream>>>(Qb, Kb, Vtb, Mw, Op0, Op1, Lp0, Lp1);
  attn_merge<<<4096, 256, 0, stream>>>(Op0, Op1, Lp0, Lp1, Qb);   // Qb now = AO
  gemm_out<<<256, 256, 0, stream>>>(Qb, wo, (float*)d_out);
}

// Round 15
// 132.955 us; speedup vs baseline: 1.0599x; 1.0599x over previous
//
#include <hip/hip_runtime.h>
#include <stdint.h>

// ---------------------------------------------------------------------------
// CustomGPT2MultiHeadAttention: B=4, S=1024, SI=512, D=1024, H=16, Dh=64
// Round 15: attn -> 512-thread / 8-wave blocks (2 q-tiles share ONE K/V
// tile): staging traffic halves, LDS/wave drops 6.4->4.35 KB, wave-level
// code identical to the R11 known-good. Grid 512. gemm_qkv/gemm_out = R11
// exact. KV-split + merge dropped (R14 null + overhead).
// ---------------------------------------------------------------------------

typedef unsigned short u16;
typedef short bf16x8v __attribute__((ext_vector_type(8)));
typedef float f32x4 __attribute__((ext_vector_type(4)));

__device__ __forceinline__ u16 f2bf(float f) {
  union { float f; uint32_t u; } x; x.f = f;
  uint32_t r = x.u + 0x7FFFu + ((x.u >> 16) & 1u);   // round-to-nearest-even
  return (u16)(r >> 16);
}

// v_cvt_pk_bf16_f32: D[15:0]=bf16(a), D[31:16]=bf16(b), RNE
__device__ __forceinline__ uint32_t cvtpk(float a, float b) {
  uint32_t r;
  asm("v_cvt_pk_bf16_f32 %0, %1, %2" : "=v"(r) : "v"(a), "v"(b));
  return r;
}

// p = bit(msrc,off) ? e : 0   via sign-extended 1-bit field + AND (2 VALU)
__device__ __forceinline__ float maskand(float e, uint32_t msrc, int off) {
  uint32_t mm = (uint32_t)((int32_t)(msrc << (31 - off)) >> 31);
  union { float f; uint32_t u; } x; x.f = e; x.u &= mm; return x.f;
}

__device__ __forceinline__ void gl_lds16(const u16* g, u16* l) {
  __builtin_amdgcn_global_load_lds((const __attribute__((address_space(1))) unsigned int*)g,
                                   (__attribute__((address_space(3))) unsigned int*)l,
                                   16, 0, 0);
}

// ---------------------------------------------------------------------------
// Fused QKV GEMM (round-11 exact): 256x256 tile, BK=64, 512 thr / 8 waves,
// dbuf, fp32 inputs with in-kernel cast, fused mask bit-pack, vectorized
// V-epilogue, XCD-affine remap.
__global__ __launch_bounds__(512, 2) void gemm_qkv(
    const float* __restrict__ Hs, const float* __restrict__ Im,
    const float* __restrict__ Wq, const float* __restrict__ Wk, const float* __restrict__ Wv,
    const float* __restrict__ Uk, const float* __restrict__ Uv,
    const int* __restrict__ Mk,
    u16* __restrict__ Qd, u16* __restrict__ Kd, u16* __restrict__ Vd,
    uint32_t* __restrict__ Mw)
{
  __shared__ __align__(16) u16 As[2 * 16384];   // 64 KB
  __shared__ __align__(16) u16 Bs[2 * 16384];   // 64 KB
  const int hb = blockIdx.x;
  const int xcd = hb & 7, slot = hb >> 3;
  int bid = (slot < 24) ? xcd * 24 + slot : 192 + xcd * 8 + (slot - 24);
  const float *Ap, *Bp;
  int bm, bn, mode;
  if (bid < 192) { mode = 4; bm = (bid / 12) * 256; bn = (bid % 12) * 256;
                   Ap = Hs + (size_t)bm * 1024;
                   Bp = ((bn < 1024) ? Wq : (bn < 2048) ? Wk : Wv) + (size_t)(bn & 1023) * 1024; }
  else           { mode = 5; int r = bid - 192; bm = (r >> 3) * 256; bn = (r & 7) * 256;
                   Ap = Im + (size_t)bm * 1024;
                   Bp = ((bn < 1024) ? Uk : Uv) + (size_t)(bn & 1023) * 1024; }
  const int tid = threadIdx.x, lane = tid & 63, wave = tid >> 6;
  const int wr = wave >> 2, wc = wave & 3;      // 2M x 4N
  const int g = lane >> 4, c = lane & 15, cs = c & 7;
  const int srow = tid >> 3;                    // 0..63
  const int pch  = tid & 7;
  const int gsw  = (pch ^ (srow & 7)) * 8;      // pre-swizzled global elem chunk

  f32x4 zf = {0.f, 0.f, 0.f, 0.f};
  f32x4 acc[8][4];
  #pragma unroll
  for (int f = 0; f < 8; ++f)
    #pragma unroll
    for (int nf = 0; nf < 4; ++nf) acc[f][nf] = zf;

  float4 sa[4][2], sb[4][2];

  #define LOAD_A(kt)                                                               \
    _Pragma("unroll")                                                              \
    for (int j_ = 0; j_ < 4; ++j_) {                                               \
      const float* p_ = Ap + (size_t)(j_ * 64 + srow) * 1024 + (kt) * 64 + gsw;    \
      sa[j_][0] = *(const float4*)p_;                                              \
      sa[j_][1] = *(const float4*)(p_ + 4);                                        \
    }
  #define LOAD_B(kt)                                                               \
    _Pragma("unroll")                                                              \
    for (int j_ = 0; j_ < 4; ++j_) {                                               \
      const float* p_ = Bp + (size_t)(j_ * 64 + srow) * 1024 + (kt) * 64 + gsw;    \
      sb[j_][0] = *(const float4*)p_;                                              \
      sb[j_][1] = *(const float4*)(p_ + 4);                                        \
    }
  #define CVT_A(buf)                                                               \
    _Pragma("unroll")                                                              \
    for (int j_ = 0; j_ < 4; ++j_) {                                               \
      uint4 w_;                                                                    \
      w_.x = cvtpk(sa[j_][0].x, sa[j_][0].y);                                      \
      w_.y = cvtpk(sa[j_][0].z, sa[j_][0].w);                                      \
      w_.z = cvtpk(sa[j_][1].x, sa[j_][1].y);                                      \
      w_.w = cvtpk(sa[j_][1].z, sa[j_][1].w);                                      \
      *(uint4*)&As[(buf) + (j_ * 64 + srow) * 64 + pch * 8] = w_;                  \
    }
  #define CVT_B(buf)                                                               \
    _Pragma("unroll")                                                              \
    for (int j_ = 0; j_ < 4; ++j_) {                                               \
      uint4 w_;                                                                    \
      w_.x = cvtpk(sb[j_][0].x, sb[j_][0].y);                                      \
      w_.y = cvtpk(sb[j_][0].z, sb[j_][0].w);                                      \
      w_.z = cvtpk(sb[j_][1].x, sb[j_][1].y);                                      \
      w_.w = cvtpk(sb[j_][1].z, sb[j_][1].w);                                      \
      *(uint4*)&Bs[(buf) + (j_ * 64 + srow) * 64 + pch * 8] = w_;                  \
    }

  // prologue: issue tile-0 loads, then pack mask (overlaps tile-0 latency)
  LOAD_A(0); LOAD_B(0);
  {
    const int fid = hb * 512 + tid;   // 131,072 threads; 196,608 words
    #pragma unroll 1
    for (int w = fid; w < 196608; w += 131072) {
      const int4* p = (const int4*)(Mk + (size_t)w * 32);
      uint32_t bits = 0;
      #pragma unroll 1
      for (int h_ = 0; h_ < 2; ++h_) {       // two batches of 4 int4 (reg cap)
        int4 v0 = p[h_ * 4 + 0], v1 = p[h_ * 4 + 1];
        int4 v2 = p[h_ * 4 + 2], v3 = p[h_ * 4 + 3];
        int bo = h_ * 16;
        bits |= (uint32_t)(v0.x != 0) << (bo + 0);
        bits |= (uint32_t)(v0.y != 0) << (bo + 1);
        bits |= (uint32_t)(v0.z != 0) << (bo + 2);
        bits |= (uint32_t)(v0.w != 0) << (bo + 3);
        bits |= (uint32_t)(v1.x != 0) << (bo + 4);
        bits |= (uint32_t)(v1.y != 0) << (bo + 5);
        bits |= (uint32_t)(v1.z != 0) << (bo + 6);
        bits |= (uint32_t)(v1.w != 0) << (bo + 7);
        bits |= (uint32_t)(v2.x != 0) << (bo + 8);
        bits |= (uint32_t)(v2.y != 0) << (bo + 9);
        bits |= (uint32_t)(v2.z != 0) << (bo + 10);
        bits |= (uint32_t)(v2.w != 0) << (bo + 11);
        bits |= (uint32_t)(v3.x != 0) << (bo + 12);
        bits |= (uint32_t)(v3.y != 0) << (bo + 13);
        bits |= (uint32_t)(v3.z != 0) << (bo + 14);
        bits |= (uint32_t)(v3.w != 0) << (bo + 15);
      }
      Mw[w] = bits;
    }
  }
  CVT_A(0);  CVT_B(0);
  __syncthreads();

  for (int kt = 0; kt < 16; ++kt) {
    const int bc = (kt & 1) * 16384;
    const int bx = bc ^ 16384;
    if (kt < 15) LOAD_A(kt + 1);       // fire-and-forget, lands during phases 0-1

    bf16x8v Bf[4][2];
    #pragma unroll
    for (int nf = 0; nf < 4; ++nf)
      #pragma unroll
      for (int ks = 0; ks < 2; ++ks)
        Bf[nf][ks] = *(const bf16x8v*)&Bs[bc + (wc * 64 + nf * 16 + c) * 64 + ((ks * 4 + g) ^ cs) * 8];

    #pragma unroll
    for (int p = 0; p < 4; ++p) {
      bf16x8v Af[2][2];
      #pragma unroll
      for (int i = 0; i < 2; ++i)
        #pragma unroll
        for (int ks = 0; ks < 2; ++ks)
          Af[i][ks] = *(const bf16x8v*)&As[bc + (wr * 128 + (p * 2 + i) * 16 + c) * 64 + ((ks * 4 + g) ^ cs) * 8];
      __builtin_amdgcn_s_setprio(1);
      #pragma unroll
      for (int i = 0; i < 2; ++i)
        #pragma unroll
        for (int nf = 0; nf < 4; ++nf)
          #pragma unroll
          for (int ks = 0; ks < 2; ++ks)
            acc[p * 2 + i][nf] =
              __builtin_amdgcn_mfma_f32_16x16x32_bf16(Af[i][ks], Bf[nf][ks], acc[p * 2 + i][nf], 0, 0, 0);
      __builtin_amdgcn_s_setprio(0);
      if (p == 1 && kt < 15) {
        __builtin_amdgcn_sched_barrier(0);   // keep cvt below phases 0-1
        CVT_A(bx);                           // A regs landed; write buf bx
        LOAD_B(kt + 1);                      // B loads land during phases 2-3
        __builtin_amdgcn_sched_barrier(0);
      }
    }
    if (kt < 15) {
      __builtin_amdgcn_sched_barrier(0);
      CVT_B(bx);
    }
    __syncthreads();                         // reads of bc done; bx writes visible
  }
  #undef LOAD_A
  #undef LOAD_B
  #undef CVT_A
  #undef CVT_B

  // epilogue — whole block is ONE region (bn is 256-aligned)
  const int gn0 = bn + wc * 64;
  if (mode == 4) {
    if (bn < 1024) {
      #pragma unroll
      for (int f = 0; f < 8; ++f)
        #pragma unroll
        for (int nf = 0; nf < 4; ++nf) {
          int gm = bm + wr * 128 + f * 16 + 4 * g;
          int gn = gn0 + nf * 16 + c;
          #pragma unroll
          for (int j = 0; j < 4; ++j)
            Qd[(size_t)(gm + j) * 1024 + gn] = f2bf(acc[f][nf][j] * 0.18033688011112042f);
        }
    } else if (bn < 2048) {
      #pragma unroll
      for (int f = 0; f < 8; ++f)
        #pragma unroll
        for (int nf = 0; nf < 4; ++nf) {
          int gm = bm + wr * 128 + f * 16 + 4 * g;
          int b_ = gm >> 10, s_ = gm & 1023;
          int gn = gn0 - 1024 + nf * 16 + c;
          #pragma unroll
          for (int j = 0; j < 4; ++j)
            Kd[(size_t)(b_ * 1536 + s_ + j) * 1024 + gn] = f2bf(acc[f][nf][j]);
        }
    } else {
      #pragma unroll
      for (int f = 0; f < 8; ++f)
        #pragma unroll
        for (int nf = 0; nf < 4; ++nf) {
          int gm = bm + wr * 128 + f * 16 + 4 * g;
          int b_ = gm >> 10, s_ = gm & 1023;
          int d_ = gn0 - 2048 + nf * 16 + c;
          uint2 st;
          st.x = cvtpk(acc[f][nf][0], acc[f][nf][1]);
          st.y = cvtpk(acc[f][nf][2], acc[f][nf][3]);
          *(uint2*)&Vd[(size_t)(b_ * 1024 + d_) * 1536 + s_] = st;
        }
    }
  } else {
    if (bn < 1024) {
      #pragma unroll
      for (int f = 0; f < 8; ++f)
        #pragma unroll
        for (int nf = 0; nf < 4; ++nf) {
          int gm = bm + wr * 128 + f * 16 + 4 * g;
          int b_ = gm >> 9, s_ = gm & 511;
          int gn = gn0 + nf * 16 + c;
          #pragma unroll
          for (int j = 0; j < 4; ++j)
            Kd[(size_t)(b_ * 1536 + 1024 + s_ + j) * 1024 + gn] = f2bf(acc[f][nf][j]);
        }
    } else {
      #pragma unroll
      for (int f = 0; f < 8; ++f)
        #pragma unroll
        for (int nf = 0; nf < 4; ++nf) {
          int gm = bm + wr * 128 + f * 16 + 4 * g;
          int b_ = gm >> 9, s_ = gm & 511;
          int d_ = gn0 - 1024 + nf * 16 + c;
          uint2 st;
          st.x = cvtpk(acc[f][nf][0], acc[f][nf][1]);
          st.y = cvtpk(acc[f][nf][2], acc[f][nf][3]);
          *(uint2*)&Vd[(size_t)(b_ * 1024 + d_) * 1536 + 1024 + s_] = st;
        }
    }
  }
}

// ---------------------------------------------------------------------------
// out-proj GEMM (round-11 exact): 128x128 tile, BK=64, 256 thr / 4 waves,
// dbuf. A = attn-out bf16 via gl_lds; B = w_o fp32 reg-staged.
__global__ __launch_bounds__(256) void gemm_out(const u16* __restrict__ A, const float* __restrict__ Bw,
                                                float* __restrict__ Cout)
{
  __shared__ __align__(16) u16 As2[2 * 8192];   // 32 KB
  __shared__ __align__(16) u16 Bs2[2 * 8192];   // 32 KB
  const int hb = blockIdx.x;
  const int xcd = hb & 7, slot = hb >> 3;       // slot 0..31
  const int rg = xcd * 4 + (slot >> 3);         // 0..31
  const int cg = slot & 7;                      // 0..7
  const int bm = rg * 128, bn = cg * 128;
  const int tid  = threadIdx.x;
  const int lane = tid & 63, wave = tid >> 6;
  const int wr = wave >> 1, wc = wave & 1;
  const int g = lane >> 4, c = lane & 15, cs = c & 7;
  const int sr  = tid >> 3;                     // 0..31
  const int pch = tid & 7;
  const int gsw = (pch ^ (sr & 7)) * 8;

  f32x4 zf = {0.f, 0.f, 0.f, 0.f};
  f32x4 acc[4][4];
  #pragma unroll
  for (int mi = 0; mi < 4; ++mi)
    #pragma unroll
    for (int ni = 0; ni < 4; ++ni) acc[mi][ni] = zf;

  float4 sb[4][2];

  #define STG_A(buf, kt)                                                           \
    _Pragma("unroll")                                                              \
    for (int q_ = 0; q_ < 4; ++q_) {                                               \
      int row_ = q_ * 32 + sr;                                                     \
      gl_lds16(A + (size_t)(bm + row_) * 1024 + (kt) * 64 + gsw,                   \
               &As2[(buf) + row_ * 64 + pch * 8]);                                 \
    }
  #define LOAD_B(kt)                                                               \
    _Pragma("unroll")                                                              \
    for (int q_ = 0; q_ < 4; ++q_) {                                               \
      const float* p_ = Bw + (size_t)(bn + q_ * 32 + sr) * 1024 + (kt) * 64 + gsw; \
      sb[q_][0] = *(const float4*)p_;                                              \
      sb[q_][1] = *(const float4*)(p_ + 4);                                        \
    }
  #define CVT_B(buf)                                                               \
    _Pragma("unroll")                                                              \
    for (int q_ = 0; q_ < 4; ++q_) {                                               \
      uint4 w_;                                                                    \
      w_.x = cvtpk(sb[q_][0].x, sb[q_][0].y);                                      \
      w_.y = cvtpk(sb[q_][0].z, sb[q_][0].w);                                      \
      w_.z = cvtpk(sb[q_][1].x, sb[q_][1].y);                                      \
      w_.w = cvtpk(sb[q_][1].z, sb[q_][1].w);                                      \
      *(uint4*)&Bs2[(buf) + (q_ * 32 + sr) * 64 + pch * 8] = w_;                   \
    }

  STG_A(0, 0);
  LOAD_B(0);
  CVT_B(0);
  __syncthreads();

  for (int kt = 0; kt < 16; ++kt) {
    const int bc = (kt & 1) * 8192;
    const int bx = bc ^ 8192;
    if (kt < 15) { STG_A(bx, kt + 1); LOAD_B(kt + 1); }

    #pragma unroll
    for (int ks = 0; ks < 2; ++ks) {
      bf16x8v af[4], bfr[4];
      #pragma unroll
      for (int mi = 0; mi < 4; ++mi)
        af[mi] = *(const bf16x8v*)&As2[bc + (wr * 64 + mi * 16 + c) * 64 + ((ks * 4 + g) ^ cs) * 8];
      #pragma unroll
      for (int ni = 0; ni < 4; ++ni)
        bfr[ni] = *(const bf16x8v*)&Bs2[bc + (wc * 64 + ni * 16 + c) * 64 + ((ks * 4 + g) ^ cs) * 8];
      __builtin_amdgcn_s_setprio(1);
      #pragma unroll
      for (int mi = 0; mi < 4; ++mi)
        #pragma unroll
        for (int ni = 0; ni < 4; ++ni)
          acc[mi][ni] = __builtin_amdgcn_mfma_f32_16x16x32_bf16(af[mi], bfr[ni], acc[mi][ni], 0, 0, 0);
      __builtin_amdgcn_s_setprio(0);
    }
    if (kt < 15) {
      __builtin_amdgcn_sched_barrier(0);
      CVT_B(bx);
    }
    __syncthreads();
  }
  #undef STG_A
  #undef LOAD_B
  #undef CVT_B

  #pragma unroll
  for (int mi = 0; mi < 4; ++mi)
    #pragma unroll
    for (int ni = 0; ni < 4; ++ni)
      #pragma unroll
      for (int j = 0; j < 4; ++j) {
        int gm = bm + wr * 64 + mi * 16 + 4 * g + j;
        int gn = bn + wc * 64 + ni * 16 + c;
        Cout[(size_t)gm * 1024 + gn] = acc[mi][ni][j];
      }
}

// ---------------------------------------------------------------------------
// flash attention, swapped QK^T, max-free softmax. R15: 512 threads / 8
// waves per block; 2 q-tiles (128 rows) share ONE K/V tile. Staging = 1
// K-chunk + 1 V-chunk per thread (was 2+2 at 256 thr). Per-wave compute,
// swizzle, softmax, and epilogue IDENTICAL to the R11 known-good.
__global__ __launch_bounds__(512) void attn_kernel(const u16* __restrict__ Q, const u16* __restrict__ Kc,
                                                   const u16* __restrict__ Vt,
                                                   const uint32_t* __restrict__ Mw,
                                                   u16* __restrict__ AO)
{
  const int bid = blockIdx.x;          // 0..511
  const int grp = bid & 63;            // (b,h) group; XCD = bid%8 = grp%8
  const int qt  = bid >> 6;            // 0..7
  const int h = grp & 15, b = grp >> 4;
  const int q0 = qt * 128;
  const int tid = threadIdx.x, lane = tid & 63, wave = tid >> 6;   // wave 0..7
  const int g = lane >> 4, c = lane & 15;
  const int qw = q0 + wave * 16;

  __shared__ __align__(16) u16 Ks[64 * 64];      // 8 KB  (shared by 8 waves)
  __shared__ __align__(16) u16 Vs[64 * 64];      // 8 KB  [d][l]
  __shared__ __align__(16) u16 Ps[8][16 * 72];   // 18 KB per-wave P, padded

  bf16x8v qf0, qf1;
  {
    const u16* qp = Q + (size_t)(b * 1024 + qw + c) * 1024 + h * 64 + g * 8;
    qf0 = *(const bf16x8v*)qp;
    qf1 = *(const bf16x8v*)(qp + 32);
  }
  f32x4 zf = {0.f, 0.f, 0.f, 0.f};
  f32x4 O[4];                       // O^T frag: [d=dt*16+4g+j][q=c]
  float l = 0.f;                    // per-lane partial denominator
  #pragma unroll
  for (int dt = 0; dt < 4; ++dt) O[dt] = zf;

  const int sr  = tid >> 3;         // 0..63 (row)
  const int pch = tid & 7;
  const int swz = (pch ^ (sr & 7)) * 8;   // write-side XOR swizzle
  const int cs  = c & 7;
  const u16* Kbase = Kc + (size_t)(b * 1536) * 1024 + h * 64;
  const u16* Vbase = Vt + (size_t)(b * 1024 + h * 64) * 1536;
  const uint32_t* mrow = Mw + (size_t)(b * 1024 + qw + c) * 48;

  // staging: 1 K-chunk + 1 V-chunk per thread (512 thr cover 64x64 each)
  bf16x8v kr0, vr0;
  kr0 = *(const bf16x8v*)(Kbase + (size_t)sr * 1024 + pch * 8);
  vr0 = *(const bf16x8v*)(Vbase + (size_t)sr * 1536 + pch * 8);
  *(bf16x8v*)&Ks[sr * 64 + swz] = kr0;
  *(bf16x8v*)&Vs[sr * 64 + swz] = vr0;
  __syncthreads();

  for (int kt = 0; kt < 24; ++kt) {
    if (kt < 23) {
      const int ln = (kt + 1) * 64;
      kr0 = *(const bf16x8v*)(Kbase + (size_t)(ln + sr) * 1024 + pch * 8);
      vr0 = *(const bf16x8v*)(Vbase + (size_t)sr * 1536 + ln + pch * 8);
    }
    uint2 mwv = *(const uint2*)(mrow + kt * 2);

    f32x4 s[4];
    __builtin_amdgcn_s_setprio(1);
    #pragma unroll
    for (int nt = 0; nt < 4; ++nt) {
      const u16* kr = &Ks[(nt * 16 + c) * 64];
      bf16x8v k0 = *(const bf16x8v*)&kr[(g ^ cs) * 8];
      bf16x8v k1 = *(const bf16x8v*)&kr[((4 + g) ^ cs) * 8];
      f32x4 z = zf;
      z = __builtin_amdgcn_mfma_f32_16x16x32_bf16(k0, qf0, z, 0, 0, 0);
      z = __builtin_amdgcn_mfma_f32_16x16x32_bf16(k1, qf1, z, 0, 0, 0);
      s[nt] = z;
    }
    __builtin_amdgcn_s_setprio(0);

    uint64_t mq = (((uint64_t)mwv.y << 32) | (uint64_t)mwv.x) >> (4 * g);
    uint32_t mlo = (uint32_t)mq, mhi = (uint32_t)(mq >> 32);
    #pragma unroll
    for (int nt = 0; nt < 4; ++nt) {
      uint32_t msrc = (nt < 2) ? mlo : mhi;
      #pragma unroll
      for (int j = 0; j < 4; ++j) {
        float e = exp2f(s[nt][j]);
        float p = maskand(e, msrc, 16 * (nt & 1) + j);
        s[nt][j] = p;
        l += p;
      }
    }

    u16* pw = &Ps[wave][0];
    #pragma unroll
    for (int nt = 0; nt < 4; ++nt) {
      uint2 pk2;
      pk2.x = cvtpk(s[nt][0], s[nt][1]);
      pk2.y = cvtpk(s[nt][2], s[nt][3]);
      *(uint2*)&pw[c * 72 + nt * 16 + g * 4] = pk2;
    }
    bf16x8v pb0 = *(const bf16x8v*)&pw[c * 72 + g * 8];
    bf16x8v pb1 = *(const bf16x8v*)&pw[c * 72 + 32 + g * 8];
    __builtin_amdgcn_s_setprio(1);
    #pragma unroll
    for (int dt = 0; dt < 4; ++dt) {
      const u16* vr = &Vs[(dt * 16 + c) * 64];
      bf16x8v v0 = *(const bf16x8v*)&vr[(g ^ cs) * 8];
      bf16x8v v1 = *(const bf16x8v*)&vr[((4 + g) ^ cs) * 8];
      O[dt] = __builtin_amdgcn_mfma_f32_16x16x32_bf16(v0, pb0, O[dt], 0, 0, 0);
      O[dt] = __builtin_amdgcn_mfma_f32_16x16x32_bf16(v1, pb1, O[dt], 0, 0, 0);
    }
    __builtin_amdgcn_s_setprio(0);

    __syncthreads();                 // all waves done READING Ks/Vs
    if (kt < 23) {
      *(bf16x8v*)&Ks[sr * 64 + swz] = kr0;
      *(bf16x8v*)&Vs[sr * 64 + swz] = vr0;
      __syncthreads();
    }
  }

  float r = l;
  r += __shfl_xor(r, 16);
  r += __shfl_xor(r, 32);
  float inv = 1.f / r;
  size_t ro = (size_t)(b * 1024 + qw + c) * 1024 + h * 64;
  #pragma unroll
  for (int dt = 0; dt < 4; ++dt) {
    uint2 st;
    st.x = cvtpk(O[dt][0] * inv, O[dt][1] * inv);
    st.y = cvtpk(O[dt][2] * inv, O[dt][3] * inv);
    *(uint2*)&AO[ro + dt * 16 + 4 * g] = st;
  }
}

// ---------------------------------------------------------------------------
extern "C" void kernel_launch(void* const* d_in, const int* in_sizes, int n_in,
                              void* d_out, int out_size, void* d_ws, size_t ws_size,
                              hipStream_t stream) {
  (void)in_sizes; (void)n_in; (void)out_size; (void)ws_size;
  const float* hs = (const float*)d_in[0];
  const float* im = (const float*)d_in[1];
  const int*   mk = (const int*)d_in[2];
  const float* wq = (const float*)d_in[3];
  const float* wk = (const float*)d_in[4];
  const float* wv = (const float*)d_in[5];
  const float* uk = (const float*)d_in[6];
  const float* uv = (const float*)d_in[7];
  const float* wo = (const float*)d_in[8];

  char* ws = (char*)d_ws;
  u16* Qb  = (u16*)(ws + 0);          //  8,388,608 B  Q token-major [4096][1024] (pre-scaled)
  u16* Kb  = (u16*)(ws + 8388608);    // 12,582,912 B  K concat [4][1536][1024]
  u16* Vtb = (u16*)(ws + 20971520);   // 12,582,912 B  V transposed [4][1024][1536]
  u16* AO  = (u16*)(ws + 33554432);   //  8,388,608 B  attn out bf16 [4096][1024]
  uint32_t* Mw = (uint32_t*)(ws + 41943040); // 786,432 B packed mask
  // total ws: 42,729,472 B

  gemm_qkv<<<256, 512, 0, stream>>>(hs, im, wq, wk, wv, uk, uv, mk, Qb, Kb, Vtb, Mw);
  attn_kernel<<<512, 512, 0, stream>>>(Qb, Kb, Vtb, Mw, AO);
  gemm_out<<<256, 256, 0, stream>>>(AO, wo, (float*)d_out);
}